// Round 1
// baseline (126.836 us; speedup 1.0000x reference)
//
#include <hip/hip_runtime.h>

#define NQ 4096           // B
#define TT 819200         // T
#define MUF 3.5f

__global__ __launch_bounds__(256) void asvd_kernel(
    const float* __restrict__ bu, const float* __restrict__ bi,
    const float* __restrict__ Q,  const float* __restrict__ X,
    const float* __restrict__ Y,
    const int* __restrict__ user, const int* __restrict__ item,
    const int* __restrict__ imp_items, const int* __restrict__ imp_ratings,
    const int* __restrict__ seg, float* __restrict__ out)
{
    const int b   = blockIdx.x;
    const int tid = threadIdx.x;

    // lower_bound over sorted segment_ids (all threads redundantly, no divergence)
    auto lower = [&](int key) {
        int lo = 0, hi = TT;
        while (lo < hi) {
            int mid = (lo + hi) >> 1;
            if (seg[mid] < key) lo = mid + 1; else hi = mid;
        }
        return lo;
    };
    const int start = lower(b);
    const int end   = lower(b + 1);
    const int count = end - start;

    const int   u    = user[b];
    const int   it   = item[b];
    const float bu_u = bu[u];
    const float bui  = MUF + bu_u + bi[it];

    const int g = tid >> 5;   // entry group 0..7
    const int l = tid & 31;   // lane within group: float4 slot of the 128-dim row

    const float4* __restrict__ X4 = (const float4*)X;
    const float4* __restrict__ Y4 = (const float4*)Y;
    const float4* __restrict__ Q4 = (const float4*)Q;

    float4 acc = make_float4(0.f, 0.f, 0.f, 0.f);
    for (int t = start + g; t < end; t += 8) {
        const int   j = imp_items[t];
        const float w = (float)imp_ratings[t] - MUF - bu_u - bi[j];
        const float4 x = X4[(size_t)j * 32 + l];
        const float4 y = Y4[(size_t)j * 32 + l];
        acc.x += w * x.x + y.x;
        acc.y += w * x.y + y.y;
        acc.z += w * x.z + y.z;
        acc.w += w * x.w + y.w;
    }

    const float4 q = Q4[(size_t)it * 32 + l];
    float partial = acc.x * q.x + acc.y * q.y + acc.z * q.z + acc.w * q.w;

    // reduce 256 threads: wave64 shuffle tree, then LDS across 4 waves
    #pragma unroll
    for (int off = 32; off > 0; off >>= 1)
        partial += __shfl_down(partial, off, 64);

    __shared__ float red[4];
    if ((tid & 63) == 0) red[tid >> 6] = partial;
    __syncthreads();
    if (tid == 0) {
        const float total = red[0] + red[1] + red[2] + red[3];
        const float norm  = (count > 0) ? rsqrtf((float)count) : 1.0f;
        out[b] = bui + norm * total;
    }
}

extern "C" void kernel_launch(void* const* d_in, const int* in_sizes, int n_in,
                              void* d_out, int out_size, void* d_ws, size_t ws_size,
                              hipStream_t stream) {
    const float* bu = (const float*)d_in[0];
    const float* bi = (const float*)d_in[1];
    const float* Q  = (const float*)d_in[2];
    const float* X  = (const float*)d_in[3];
    const float* Y  = (const float*)d_in[4];
    const int* user        = (const int*)d_in[5];
    const int* item        = (const int*)d_in[6];
    const int* imp_items   = (const int*)d_in[7];
    const int* imp_ratings = (const int*)d_in[8];
    const int* seg         = (const int*)d_in[9];
    float* out = (float*)d_out;

    asvd_kernel<<<NQ, 256, 0, stream>>>(bu, bi, Q, X, Y, user, item,
                                        imp_items, imp_ratings, seg, out);
}